// Round 22
// baseline (262.312 us; speedup 1.0000x reference)
//
#include <hip/hip_runtime.h>
#include <hip/hip_fp16.h>
#include <math.h>

#define N_USER 50000
#define N_ITEM 100000
#define E_UI   1000000
#define E_UU   800000
#define E_TOT  (E_UI + E_UI + E_UU)
#define NTOT_NODES (N_ITEM + 2 * N_USER)
#define NEG_SLOPE 0.2f
#define LOG2E 1.4426950408889634f

#define NB0 391
#define NB1 196
#define NB2 196
#define NBTOT (NB0 + NB1 + NB2)   // 783
#define GPB 256
#define MATN (NBTOT * 256)        // 200448
#define NBP  ((MATN + 1023) / 1024)  // 196 partials

#define XS_STRIDE 68

typedef _Float16 h2v __attribute__((ext_vector_type(2)));

#if defined(__has_builtin)
#if __has_builtin(__builtin_amdgcn_fdot2)
#define HAS_FDOT2 1
#endif
#if __has_builtin(__builtin_elementwise_max)
#define HAS_EW_MAX 1
#endif
#if __has_builtin(__builtin_amdgcn_exp2f)
#define HAS_EXP2 1
#endif
#endif

__device__ __forceinline__ float fexp2(float x) {
#ifdef HAS_EXP2
  return __builtin_amdgcn_exp2f(x);
#else
  return exp2f(x);
#endif
}

__device__ __forceinline__ float fdot2acc(__half2 a, __half2 b, float c) {
#ifdef HAS_FDOT2
  return __builtin_amdgcn_fdot2(__builtin_bit_cast(h2v, a), __builtin_bit_cast(h2v, b), c, false);
#else
  float2 af = __half22float2(a), bf = __half22float2(b);
  return fmaf(af.x, bf.x, fmaf(af.y, bf.y, c));
#endif
}

__device__ __forceinline__ __half2 h2max(__half2 a, __half2 b) {
  h2v av = __builtin_bit_cast(h2v, a), bv = __builtin_bit_cast(h2v, b);
#ifdef HAS_EW_MAX
  h2v r = __builtin_elementwise_max(av, bv);
#else
  h2v r; r.x = av.x > bv.x ? av.x : bv.x; r.y = av.y > bv.y ? av.y : bv.y;
#endif
  return __builtin_bit_cast(__half2, r);
}

__device__ __forceinline__ __half2 h2min(__half2 a, __half2 b) {
  h2v av = __builtin_bit_cast(h2v, a), bv = __builtin_bit_cast(h2v, b);
#ifdef HAS_EW_MAX
  h2v r = __builtin_elementwise_min(av, bv);
#else
  h2v r; r.x = av.x < bv.x ? av.x : bv.x; r.y = av.y < bv.y ? av.y : bv.y;
#endif
  return __builtin_bit_cast(__half2, r);
}

// ---------------- bucket histogram ----------------

__global__ __launch_bounds__(256) void bucket_hist(const int* __restrict__ d0, const int* __restrict__ d1,
                                                   const int* __restrict__ d2, int* __restrict__ mat) {
  int gid = blockIdx.x >> 8;
  int g   = blockIdx.x & 255;
  const int* dst = gid == 0 ? d0 : (gid == 1 ? d1 : d2);
  int E    = (gid == 2) ? E_UU : E_UI;
  int NB   = (gid == 0) ? NB0 : NB1;
  int boff = (gid == 0) ? 0 : (gid == 1 ? NB0 : NB0 + NB1);
  __shared__ int cnt[NB0];
  for (int b = threadIdx.x; b < NB; b += 256) cnt[b] = 0;
  __syncthreads();
  int chunk = (E + 255) >> 8;
  int lo = g * chunk, hi = min(lo + chunk, E);
  for (int i = lo + threadIdx.x; i < hi; i += 256)
    atomicAdd(&cnt[dst[i] >> 8], 1);
  __syncthreads();
  for (int b = threadIdx.x; b < NB; b += 256)
    mat[(boff + b) * 256 + g] = cnt[b];
}

// ---------------- scan: partials + fused apply ----------------

__global__ __launch_bounds__(256) void partial_kernel(const int* __restrict__ counts, int n,
                                                      int* __restrict__ partials) {
  int t = threadIdx.x;
  int base = blockIdx.x * 1024 + t * 4;
  int s = 0;
  if (base + 3 < n) {
    int4 v = *(const int4*)(counts + base);
    s = v.x + v.y + v.z + v.w;
  } else {
    for (int i = base; i < n && i < base + 4; ++i) s += counts[i];
  }
  #pragma unroll
  for (int off = 1; off < 64; off <<= 1) s += __shfl_xor(s, off);
  __shared__ int ws[4];
  if ((t & 63) == 0) ws[t >> 6] = s;
  __syncthreads();
  if (t == 0) partials[blockIdx.x] = ws[0] + ws[1] + ws[2] + ws[3];
}

__global__ __launch_bounds__(256) void scan_apply_fused(const int* __restrict__ counts, int n,
                                                        const int* __restrict__ partials, int nbp,
                                                        int* __restrict__ outp) {
  __shared__ int sp[256];
  int t = threadIdx.x;
  sp[t] = (t < nbp) ? partials[t] : 0;
  __syncthreads();
  for (int off = 1; off < 256; off <<= 1) {
    int v = (t >= off) ? sp[t - off] : 0;
    __syncthreads();
    sp[t] += v;
    __syncthreads();
  }
  int block_off = (blockIdx.x == 0) ? 0 : sp[blockIdx.x - 1];

  int base = blockIdx.x * 1024 + t * 4;
  int4 v = make_int4(0, 0, 0, 0);
  if (base + 3 < n) {
    v = *(const int4*)(counts + base);
  } else {
    int* pv = &v.x;
    for (int i = 0; i < 4; ++i) if (base + i < n) pv[i] = counts[base + i];
  }
  int s = v.x + v.y + v.z + v.w;
  int lane = t & 63;
  int wv = t >> 6;
  int inc = s;
  #pragma unroll
  for (int off = 1; off < 64; off <<= 1) {
    int u = __shfl_up(inc, off);
    if (lane >= off) inc += u;
  }
  __shared__ int wsum[4];
  if (lane == 63) wsum[wv] = inc;
  __syncthreads();
  int woff = 0;
  for (int i = 0; i < wv; ++i) woff += wsum[i];
  int excl = woff + (inc - s) + block_off;
  int4 rp;
  rp.x = excl;
  rp.y = rp.x + v.x;
  rp.z = rp.y + v.y;
  rp.w = rp.z + v.z;
  if (base + 3 < n) {
    *(int4*)(outp + base) = rp;
  } else {
    int* pr = &rp.x;
    for (int i = 0; i < 4; ++i) if (base + i < n) outp[base + i] = pr[i];
  }
}

// ---------------- bucket scatter ----------------

__global__ __launch_bounds__(256) void bucket_scatter(const int* __restrict__ s0v, const int* __restrict__ d0,
                                                      const int* __restrict__ s1v, const int* __restrict__ d1,
                                                      const int* __restrict__ s2v, const int* __restrict__ d2,
                                                      const int* __restrict__ mscan, unsigned int* __restrict__ pairs) {
  int gid = blockIdx.x >> 8;
  int g   = blockIdx.x & 255;
  const int* src = gid == 0 ? s0v : (gid == 1 ? s1v : s2v);
  const int* dst = gid == 0 ? d0  : (gid == 1 ? d1  : d2);
  int E    = (gid == 2) ? E_UU : E_UI;
  int NB   = (gid == 0) ? NB0 : NB1;
  int boff = (gid == 0) ? 0 : (gid == 1 ? NB0 : NB0 + NB1);
  __shared__ int cur[NB0];
  for (int b = threadIdx.x; b < NB; b += 256) cur[b] = mscan[(boff + b) * 256 + g];
  __syncthreads();
  int chunk = (E + 255) >> 8;
  int lo = g * chunk, hi = min(lo + chunk, E);
  for (int i = lo + threadIdx.x; i < hi; i += 256) {
    int d = dst[i], s = src[i];
    int pos = atomicAdd(&cur[d >> 8], 1);
    pairs[pos] = ((unsigned)(d & 255) << 24) | (unsigned)s;
  }
}

// ---------------- bucket finalize ----------------

__global__ __launch_bounds__(256) void bucket_finalize(const unsigned int* __restrict__ pairs,
                                                       const int* __restrict__ mscan,
                                                       int* __restrict__ rp, int* __restrict__ col) {
  int gb = blockIdx.x;
  int t  = threadIdx.x;
  int gid  = (gb < NB0) ? 0 : (gb < NB0 + NB1 ? 1 : 2);
  int boff = (gid == 0) ? 0 : (gid == 1 ? NB0 : NB0 + NB1);
  int node_goff = (gid == 0) ? 0 : (gid == 1 ? N_ITEM : N_ITEM + N_USER);
  int n    = (gid == 0) ? N_ITEM : N_USER;
  int b_local = gb - boff;
  int bs = mscan[gb * 256];
  int be = (gb + 1 < NBTOT) ? mscan[(gb + 1) * 256] : E_TOT;

  __shared__ int cnt[256];
  __shared__ int curb[256];
  __shared__ int wsum[4];
  cnt[t] = 0;
  __syncthreads();
  for (int i = bs + t; i < be; i += 256)
    atomicAdd(&cnt[pairs[i] >> 24], 1);
  __syncthreads();

  int v = cnt[t];
  int lane = t & 63, wv = t >> 6;
  int inc = v;
  #pragma unroll
  for (int off = 1; off < 64; off <<= 1) {
    int u = __shfl_up(inc, off);
    if (lane >= off) inc += u;
  }
  if (lane == 63) wsum[wv] = inc;
  __syncthreads();
  int woff = 0;
  for (int i = 0; i < wv; ++i) woff += wsum[i];
  int base = bs + woff + (inc - v);

  int node_local = b_local * 256 + t;
  if (node_local < n) rp[node_goff + node_local] = base;
  if (gb == NBTOT - 1 && t == 255) rp[N_ITEM + 2 * N_USER] = E_TOT;
  curb[t] = base;
  __syncthreads();

  for (int i = bs + t; i < be; i += 256) {
    unsigned u = pairs[i];
    int p = atomicAdd(&curb[u >> 24], 1);
    col[p] = (int)(u & 0xFFFFFFu);
  }
}

// ---------------- GEMM building blocks (LDS-staged X, unroll-capped) ----------------

__device__ __forceinline__ void load_xtile(const float* __restrict__ X, float* Xs, int base, int N) {
  #pragma unroll
  for (int i = 0; i < 4; ++i) {
    int idx = threadIdx.x * 4 + i * 1024;
    int row = idx >> 6, colc = idx & 63;
    int grow = base + row;
    const float* src = X + (size_t)(grow < N ? grow : N - 1) * 64 + colc;
    *(float4*)(Xs + row * XS_STRIDE + colc) = *(const float4*)src;
  }
}

__device__ __forceinline__ void gemm_phase(const float* __restrict__ Wsrc, float* Ws,
                                           const float* x0, const float* x1,
                                           const float* x2, const float* x3, int c4,
                                           float4& acc0, float4& acc1, float4& acc2, float4& acc3) {
  __syncthreads();
  #pragma unroll
  for (int i = 0; i < 4; ++i) {
    int idx = threadIdx.x * 4 + i * 1024;
    *(float4*)(Ws + idx) = *(const float4*)(Wsrc + idx);
  }
  __syncthreads();
  acc0 = make_float4(0.f, 0.f, 0.f, 0.f);
  acc1 = acc0; acc2 = acc0; acc3 = acc0;
  #pragma unroll 4
  for (int k4 = 0; k4 < 64; k4 += 4) {
    float4 xa = *(const float4*)(x0 + k4);
    float4 xb = *(const float4*)(x1 + k4);
    float4 xc = *(const float4*)(x2 + k4);
    float4 xd = *(const float4*)(x3 + k4);
    #pragma unroll
    for (int kk = 0; kk < 4; ++kk) {
      float4 w = *(const float4*)(Ws + (k4 + kk) * 64 + c4);
      float sa = (&xa.x)[kk], sb = (&xb.x)[kk], sc = (&xc.x)[kk], sd = (&xd.x)[kk];
      acc0.x = fmaf(sa, w.x, acc0.x); acc0.y = fmaf(sa, w.y, acc0.y);
      acc0.z = fmaf(sa, w.z, acc0.z); acc0.w = fmaf(sa, w.w, acc0.w);
      acc1.x = fmaf(sb, w.x, acc1.x); acc1.y = fmaf(sb, w.y, acc1.y);
      acc1.z = fmaf(sb, w.z, acc1.z); acc1.w = fmaf(sb, w.w, acc1.w);
      acc2.x = fmaf(sc, w.x, acc2.x); acc2.y = fmaf(sc, w.y, acc2.y);
      acc2.z = fmaf(sc, w.z, acc2.z); acc2.w = fmaf(sc, w.w, acc2.w);
      acc3.x = fmaf(sd, w.x, acc3.x); acc3.y = fmaf(sd, w.y, acc3.y);
      acc3.z = fmaf(sd, w.z, acc3.z); acc3.w = fmaf(sd, w.w, acc3.w);
    }
  }
}

__device__ __forceinline__ void gemm_phase_h(const float* __restrict__ Wsrc, float* Ws,
                                             const __half* x0, const __half* x1,
                                             const __half* x2, const __half* x3, int c4,
                                             float4& acc0, float4& acc1, float4& acc2, float4& acc3) {
  __syncthreads();
  #pragma unroll
  for (int i = 0; i < 4; ++i) {
    int idx = threadIdx.x * 4 + i * 1024;
    *(float4*)(Ws + idx) = *(const float4*)(Wsrc + idx);
  }
  __syncthreads();
  acc0 = make_float4(0.f, 0.f, 0.f, 0.f);
  acc1 = acc0; acc2 = acc0; acc3 = acc0;
  #pragma unroll 4
  for (int k4 = 0; k4 < 64; k4 += 4) {
    uint2 ua = *(const uint2*)(x0 + k4);
    uint2 ub = *(const uint2*)(x1 + k4);
    uint2 uc = *(const uint2*)(x2 + k4);
    uint2 ud = *(const uint2*)(x3 + k4);
    float2 fa0 = __half22float2(__builtin_bit_cast(__half2, ua.x));
    float2 fa1 = __half22float2(__builtin_bit_cast(__half2, ua.y));
    float2 fb0 = __half22float2(__builtin_bit_cast(__half2, ub.x));
    float2 fb1 = __half22float2(__builtin_bit_cast(__half2, ub.y));
    float2 fc0 = __half22float2(__builtin_bit_cast(__half2, uc.x));
    float2 fc1 = __half22float2(__builtin_bit_cast(__half2, uc.y));
    float2 fd0 = __half22float2(__builtin_bit_cast(__half2, ud.x));
    float2 fd1 = __half22float2(__builtin_bit_cast(__half2, ud.y));
    float xav[4] = {fa0.x, fa0.y, fa1.x, fa1.y};
    float xbv[4] = {fb0.x, fb0.y, fb1.x, fb1.y};
    float xcv[4] = {fc0.x, fc0.y, fc1.x, fc1.y};
    float xdv[4] = {fd0.x, fd0.y, fd1.x, fd1.y};
    #pragma unroll
    for (int kk = 0; kk < 4; ++kk) {
      float4 w = *(const float4*)(Ws + (k4 + kk) * 64 + c4);
      float sa = xav[kk], sb = xbv[kk], sc = xcv[kk], sd = xdv[kk];
      acc0.x = fmaf(sa, w.x, acc0.x); acc0.y = fmaf(sa, w.y, acc0.y);
      acc0.z = fmaf(sa, w.z, acc0.z); acc0.w = fmaf(sa, w.w, acc0.w);
      acc1.x = fmaf(sb, w.x, acc1.x); acc1.y = fmaf(sb, w.y, acc1.y);
      acc1.z = fmaf(sb, w.z, acc1.z); acc1.w = fmaf(sb, w.w, acc1.w);
      acc2.x = fmaf(sc, w.x, acc2.x); acc2.y = fmaf(sc, w.y, acc2.y);
      acc2.z = fmaf(sc, w.z, acc2.z); acc2.w = fmaf(sc, w.w, acc2.w);
      acc3.x = fmaf(sd, w.x, acc3.x); acc3.y = fmaf(sd, w.y, acc3.y);
      acc3.z = fmaf(sd, w.z, acc3.z); acc3.w = fmaf(sd, w.w, acc3.w);
    }
  }
}

__device__ __forceinline__ void store4_f16(__half* __restrict__ Y, int r0, int r1, int r2, int r3,
                                           int N, int c4,
                                           const float4& a0, const float4& a1,
                                           const float4& a2, const float4& a3) {
  uint2 st;
  if (r0 < N) {
    st.x = __builtin_bit_cast(unsigned int, __floats2half2_rn(a0.x, a0.y));
    st.y = __builtin_bit_cast(unsigned int, __floats2half2_rn(a0.z, a0.w));
    *(uint2*)(Y + (size_t)r0 * 64 + c4) = st;
  }
  if (r1 < N) {
    st.x = __builtin_bit_cast(unsigned int, __floats2half2_rn(a1.x, a1.y));
    st.y = __builtin_bit_cast(unsigned int, __floats2half2_rn(a1.z, a1.w));
    *(uint2*)(Y + (size_t)r1 * 64 + c4) = st;
  }
  if (r2 < N) {
    st.x = __builtin_bit_cast(unsigned int, __floats2half2_rn(a2.x, a2.y));
    st.y = __builtin_bit_cast(unsigned int, __floats2half2_rn(a2.z, a2.w));
    *(uint2*)(Y + (size_t)r2 * 64 + c4) = st;
  }
  if (r3 < N) {
    st.x = __builtin_bit_cast(unsigned int, __floats2half2_rn(a3.x, a3.y));
    st.y = __builtin_bit_cast(unsigned int, __floats2half2_rn(a3.z, a3.w));
    *(uint2*)(Y + (size_t)r3 * 64 + c4) = st;
  }
}

__global__ __launch_bounds__(256) void gemm_user4(const float* __restrict__ X,
                                                  const float* __restrict__ W0, const float* __restrict__ W1,
                                                  const float* __restrict__ W2, const float* __restrict__ W3,
                                                  __half* __restrict__ Y0, __half* __restrict__ Y1,
                                                  __half* __restrict__ Y2, __half* __restrict__ Y3, int N) {
  __shared__ float Xs[64 * XS_STRIDE];
  __shared__ float Ws[64 * 64];
  int base = blockIdx.x * 64;
  load_xtile(X, Xs, base, N);
  int c4 = (threadIdx.x & 15) * 4;
  int rl = threadIdx.x >> 4;
  int r0 = base + rl, r1 = r0 + 16, r2 = r0 + 32, r3 = r0 + 48;
  const float* x0 = Xs + (rl +  0) * XS_STRIDE;
  const float* x1 = Xs + (rl + 16) * XS_STRIDE;
  const float* x2 = Xs + (rl + 32) * XS_STRIDE;
  const float* x3 = Xs + (rl + 48) * XS_STRIDE;
  float4 a0, a1, a2, a3;
  gemm_phase(W0, Ws, x0, x1, x2, x3, c4, a0, a1, a2, a3);
  store4_f16(Y0, r0, r1, r2, r3, N, c4, a0, a1, a2, a3);
  gemm_phase(W1, Ws, x0, x1, x2, x3, c4, a0, a1, a2, a3);
  store4_f16(Y1, r0, r1, r2, r3, N, c4, a0, a1, a2, a3);
  gemm_phase(W2, Ws, x0, x1, x2, x3, c4, a0, a1, a2, a3);
  store4_f16(Y2, r0, r1, r2, r3, N, c4, a0, a1, a2, a3);
  gemm_phase(W3, Ws, x0, x1, x2, x3, c4, a0, a1, a2, a3);
  store4_f16(Y3, r0, r1, r2, r3, N, c4, a0, a1, a2, a3);
}

__global__ __launch_bounds__(256) void gemm_item2(const float* __restrict__ X,
                                                  const float* __restrict__ W0, const float* __restrict__ W1,
                                                  __half* __restrict__ Y0, __half* __restrict__ Y1, int N) {
  __shared__ float Xs[64 * XS_STRIDE];
  __shared__ float Ws[64 * 64];
  int base = blockIdx.x * 64;
  load_xtile(X, Xs, base, N);
  int c4 = (threadIdx.x & 15) * 4;
  int rl = threadIdx.x >> 4;
  int r0 = base + rl, r1 = r0 + 16, r2 = r0 + 32, r3 = r0 + 48;
  const float* x0 = Xs + (rl +  0) * XS_STRIDE;
  const float* x1 = Xs + (rl + 16) * XS_STRIDE;
  const float* x2 = Xs + (rl + 32) * XS_STRIDE;
  const float* x3 = Xs + (rl + 48) * XS_STRIDE;
  float4 a0, a1, a2, a3;
  gemm_phase(W0, Ws, x0, x1, x2, x3, c4, a0, a1, a2, a3);
  store4_f16(Y0, r0, r1, r2, r3, N, c4, a0, a1, a2, a3);
  gemm_phase(W1, Ws, x0, x1, x2, x3, c4, a0, a1, a2, a3);
  store4_f16(Y1, r0, r1, r2, r3, N, c4, a0, a1, a2, a3);
}

__global__ __launch_bounds__(256) void gemm_mid2x(const __half* __restrict__ XA, const float* __restrict__ WA,
                                                  __half* __restrict__ YA, int NA, int nbA,
                                                  const __half* __restrict__ XB, const float* __restrict__ WB,
                                                  __half* __restrict__ YB, int NB_) {
  __shared__ float Ws[64 * 64];
  const __half* X; const float* W; __half* Y; int N; int base;
  if ((int)blockIdx.x < nbA) {
    X = XA; W = WA; Y = YA; N = NA; base = blockIdx.x * 64;
  } else {
    X = XB; W = WB; Y = YB; N = NB_; base = (blockIdx.x - nbA) * 64;
  }
  int c4 = (threadIdx.x & 15) * 4;
  int rl = threadIdx.x >> 4;
  int r0 = base + rl, r1 = r0 + 16, r2 = r0 + 32, r3 = r0 + 48;
  const __half* x0 = X + (size_t)(r0 < N ? r0 : N - 1) * 64;
  const __half* x1 = X + (size_t)(r1 < N ? r1 : N - 1) * 64;
  const __half* x2 = X + (size_t)(r2 < N ? r2 : N - 1) * 64;
  const __half* x3 = X + (size_t)(r3 < N ? r3 : N - 1) * 64;
  float4 a0, a1, a2, a3;
  gemm_phase_h(W, Ws, x0, x1, x2, x3, c4, a0, a1, a2, a3);
  store4_f16(Y, r0, r1, r2, r3, N, c4, a0, a1, a2, a3);
}

// ---------------- fused GATv2 v8: 8 nodes/wave, software-pipelined edge loop ----------------
// Next quad's col indices + row gathers issue while current quad computes:
// breaks the col->gather serial chain, doubles loads in flight.

__global__ __launch_bounds__(256) void gat8n_kernel(
    const __half* __restrict__ hsA, const __half* __restrict__ hdAp,
    const int* __restrict__ rpA, const float* __restrict__ attnA, const float* __restrict__ biasA,
    __half* __restrict__ outA, int NdA,
    const __half* __restrict__ hsB, const __half* __restrict__ hdBp,
    const int* __restrict__ rpB, const float* __restrict__ attnB, const float* __restrict__ biasB,
    __half* __restrict__ outB, int NdB,
    const int* __restrict__ col) {
  int w = (blockIdx.x * blockDim.x + threadIdx.x) >> 6;
  int grp = (threadIdx.x >> 3) & 7;    // 8 groups per wave
  int q   = threadIdx.x & 7;           // lane-in-group: dims [q*8, q*8+8)
  int node = w * 8 + grp;
  bool valid = node < NdA + NdB;
  bool inA = node < NdA;
  const __half* hs  = inA ? hsA  : hsB;
  const __half* hd  = inA ? hdAp : hdBp;
  const int* rp     = inA ? rpA  : rpB;
  const float* attn = inA ? attnA : attnB;
  const float* bias = inA ? biasA : biasB;
  __half* outp      = inA ? outA : outB;
  int nn = inA ? node : node - NdA;
  if (!valid) nn = 0;
  int s0 = valid ? rp[nn] : 0;
  int s1 = valid ? rp[nn + 1] : 0;

  const __half2 C02 = __floats2half2_rn(NEG_SLOPE, NEG_SLOPE);
  const __half2 Z   = __floats2half2_rn(0.f, 0.f);

  __half2 hd2[4], a2[4];
  {
    uint4 hv = *(const uint4*)(hd + (size_t)nn * 64 + q * 8);   // 8 f16 dims
    hd2[0] = __builtin_bit_cast(__half2, hv.x);
    hd2[1] = __builtin_bit_cast(__half2, hv.y);
    hd2[2] = __builtin_bit_cast(__half2, hv.z);
    hd2[3] = __builtin_bit_cast(__half2, hv.w);
    const float* ap = attn + q * 8;
    #pragma unroll
    for (int i = 0; i < 2; ++i) {
      float4 v = *(const float4*)(ap + i * 4);
      a2[2 * i]     = __floats2half2_rn(v.x * LOG2E, v.y * LOG2E);
      a2[2 * i + 1] = __floats2half2_rn(v.z * LOG2E, v.w * LOG2E);
    }
  }

  float m = -1e30f, den = 0.f;
  float num[8];
  #pragma unroll
  for (int i = 0; i < 8; ++i) num[i] = 0.f;

  // software pipeline: quad registers for current iteration, prefetched next quad
  uint4 ra, rb, rc, rd;
  bool h1 = false, h2c = false, h3 = false;
  if (s0 < s1) {
    // prologue: load first quad (clamped indices always in [s0, s1))
    int f1 = min(s0 + 1, s1 - 1), f2 = min(s0 + 2, s1 - 1), f3 = min(s0 + 3, s1 - 1);
    h1 = (s0 + 1) < s1; h2c = (s0 + 2) < s1; h3 = (s0 + 3) < s1;
    int sa = col[s0], sb = col[f1], sc = col[f2], sd = col[f3];
    ra = *(const uint4*)(hs + (size_t)sa * 64 + q * 8);
    rb = *(const uint4*)(hs + (size_t)sb * 64 + q * 8);
    rc = *(const uint4*)(hs + (size_t)sc * 64 + q * 8);
    rd = *(const uint4*)(hs + (size_t)sd * 64 + q * 8);
  } else {
    ra = rb = rc = rd = make_uint4(0, 0, 0, 0);
  }

  for (int e = s0; e < s1; e += 4) {
    // --- prefetch next quad (clamped; issues before current compute) ---
    int g0 = min(e + 4, s1 - 1), g1 = min(e + 5, s1 - 1);
    int g2 = min(e + 6, s1 - 1), g3 = min(e + 7, s1 - 1);
    bool n1 = (e + 5) < s1, n2 = (e + 6) < s1, n3 = (e + 7) < s1;
    int pa_i = col[g0], pb_i = col[g1], pc_i = col[g2], pd_i = col[g3];
    uint4 na = *(const uint4*)(hs + (size_t)pa_i * 64 + q * 8);
    uint4 nb = *(const uint4*)(hs + (size_t)pb_i * 64 + q * 8);
    uint4 nc = *(const uint4*)(hs + (size_t)pc_i * 64 + q * 8);
    uint4 nd = *(const uint4*)(hs + (size_t)pd_i * 64 + q * 8);

    // --- compute with current quad ---
    unsigned rau[4] = {ra.x, ra.y, ra.z, ra.w};
    unsigned rbu[4] = {rb.x, rb.y, rb.z, rb.w};
    unsigned rcu[4] = {rc.x, rc.y, rc.z, rc.w};
    unsigned rdu[4] = {rd.x, rd.y, rd.z, rd.w};

    float ta = 0.f, tb = 0.f, tc = 0.f, td = 0.f;
    #pragma unroll
    for (int i = 0; i < 4; ++i) {
      __half2 xa = __hadd2(__builtin_bit_cast(__half2, rau[i]), hd2[i]);
      ta = fdot2acc(a2[i], __hfma2(C02, h2min(xa, Z), h2max(xa, Z)), ta);
      __half2 xb = __hadd2(__builtin_bit_cast(__half2, rbu[i]), hd2[i]);
      tb = fdot2acc(a2[i], __hfma2(C02, h2min(xb, Z), h2max(xb, Z)), tb);
      __half2 xc = __hadd2(__builtin_bit_cast(__half2, rcu[i]), hd2[i]);
      tc = fdot2acc(a2[i], __hfma2(C02, h2min(xc, Z), h2max(xc, Z)), tc);
      __half2 xd = __hadd2(__builtin_bit_cast(__half2, rdu[i]), hd2[i]);
      td = fdot2acc(a2[i], __hfma2(C02, h2min(xd, Z), h2max(xd, Z)), td);
    }
    #pragma unroll
    for (int off = 1; off < 8; off <<= 1) {
      ta += __shfl_xor(ta, off);
      tb += __shfl_xor(tb, off);
      tc += __shfl_xor(tc, off);
      td += __shfl_xor(td, off);
    }
    if (!h1)  tb = -1e30f;
    if (!h2c) tc = -1e30f;
    if (!h3)  td = -1e30f;

    float tp = fmaxf(fmaxf(ta, tb), fmaxf(tc, td));
    float dd = tp - m;
    if (dd > 11.5f) {                 // defer-max (log2 units)
      float sc0 = fexp2(-dd);
      den *= sc0;
      #pragma unroll
      for (int i = 0; i < 8; ++i) num[i] *= sc0;
      m = tp;
    }
    float pa = fexp2(ta - m);
    float pb = fexp2(tb - m);
    float pc = fexp2(tc - m);
    float pd = fexp2(td - m);
    den += (pa + pb) + (pc + pd);
    __half2 pab = __floats2half2_rn(pa, pb);
    __half2 pcd = __floats2half2_rn(pc, pd);

    #pragma unroll
    for (int i = 0; i < 4; ++i) {
      unsigned lo_ab = (rau[i] & 0xFFFFu) | (rbu[i] << 16);
      unsigned hi_ab = (rau[i] >> 16) | (rbu[i] & 0xFFFF0000u);
      unsigned lo_cd = (rcu[i] & 0xFFFFu) | (rdu[i] << 16);
      unsigned hi_cd = (rcu[i] >> 16) | (rdu[i] & 0xFFFF0000u);
      num[2 * i]     = fdot2acc(__builtin_bit_cast(__half2, lo_cd), pcd,
                       fdot2acc(__builtin_bit_cast(__half2, lo_ab), pab, num[2 * i]));
      num[2 * i + 1] = fdot2acc(__builtin_bit_cast(__half2, hi_cd), pcd,
                       fdot2acc(__builtin_bit_cast(__half2, hi_ab), pab, num[2 * i + 1]));
    }

    // --- rotate pipeline ---
    ra = na; rb = nb; rc = nc; rd = nd;
    h1 = n1; h2c = n2; h3 = n3;
  }

  if (valid) {
    float inv = 1.f / fmaxf(den, 1e-9f);
    const float* bp = bias + q * 8;
    float4 b0 = *(const float4*)(bp);
    float4 b1 = *(const float4*)(bp + 4);
    uint4 st;
    st.x = __builtin_bit_cast(unsigned int,
        __floats2half2_rn(fmaf(num[0], inv, b0.x), fmaf(num[1], inv, b0.y)));
    st.y = __builtin_bit_cast(unsigned int,
        __floats2half2_rn(fmaf(num[2], inv, b0.z), fmaf(num[3], inv, b0.w)));
    st.z = __builtin_bit_cast(unsigned int,
        __floats2half2_rn(fmaf(num[4], inv, b1.x), fmaf(num[5], inv, b1.y)));
    st.w = __builtin_bit_cast(unsigned int,
        __floats2half2_rn(fmaf(num[6], inv, b1.z), fmaf(num[7], inv, b1.w)));
    *(uint4*)(outp + (size_t)nn * 64 + q * 8) = st;
  }
}

// ---------------- final: out = [A|B] @ Wout + bout (A,B f16) ----------------

__global__ __launch_bounds__(256) void final_kernel(const __half* __restrict__ A, const __half* __restrict__ B,
                                                    const float* __restrict__ W, const float* __restrict__ bias,
                                                    float* __restrict__ Y, int N) {
  __shared__ float Ws[128 * 64];
  #pragma unroll
  for (int i = 0; i < 8; ++i) {
    int idx = threadIdx.x * 4 + i * 1024;
    *(float4*)(Ws + idx) = *(const float4*)(W + idx);
  }
  __syncthreads();
  int c4 = (threadIdx.x & 15) * 4;
  int rl = threadIdx.x >> 4;
  int base = blockIdx.x * 64;

  float4 b4 = *(const float4*)(bias + c4);

  #pragma unroll
  for (int rr = 0; rr < 4; ++rr) {
    int row = base + rr * 16 + rl;
    if (row >= N) continue;
    const __half* ar = A + (size_t)row * 64;
    const __half* br = B + (size_t)row * 64;
    float4 acc = b4;
    #pragma unroll 4
    for (int k4 = 0; k4 < 64; k4 += 4) {
      uint2 ua = *(const uint2*)(ar + k4);
      uint2 ub = *(const uint2*)(br + k4);
      float2 fa0 = __half22float2(__builtin_bit_cast(__half2, ua.x));
      float2 fa1 = __half22float2(__builtin_bit_cast(__half2, ua.y));
      float2 fb0 = __half22float2(__builtin_bit_cast(__half2, ub.x));
      float2 fb1 = __half22float2(__builtin_bit_cast(__half2, ub.y));
      float xav[4] = {fa0.x, fa0.y, fa1.x, fa1.y};
      float xbv[4] = {fb0.x, fb0.y, fb1.x, fb1.y};
      #pragma unroll
      for (int kk = 0; kk < 4; ++kk) {
        float4 wa = *(const float4*)(Ws + (k4 + kk) * 64 + c4);
        float4 wb = *(const float4*)(Ws + (64 + k4 + kk) * 64 + c4);
        float xsa = xav[kk], xsb = xbv[kk];
        acc.x = fmaf(xsa, wa.x, acc.x); acc.x = fmaf(xsb, wb.x, acc.x);
        acc.y = fmaf(xsa, wa.y, acc.y); acc.y = fmaf(xsb, wb.y, acc.y);
        acc.z = fmaf(xsa, wa.z, acc.z); acc.z = fmaf(xsb, wb.z, acc.z);
        acc.w = fmaf(xsa, wa.w, acc.w); acc.w = fmaf(xsb, wb.w, acc.w);
      }
    }
    *(float4*)(Y + (size_t)row * 64 + c4) = acc;
  }
}

// ---------------- launch ----------------

extern "C" void kernel_launch(void* const* d_in, const int* in_sizes, int n_in,
                              void* d_out, int out_size, void* d_ws, size_t ws_size,
                              hipStream_t stream) {
  const float* h_user   = (const float*)d_in[0];
  const float* h_item   = (const float*)d_in[1];
  const int* rate_src   = (const int*)d_in[2];
  const int* rate_dst   = (const int*)d_in[3];
  const int* rb_src     = (const int*)d_in[4];
  const int* rb_dst     = (const int*)d_in[5];
  const int* link_src   = (const int*)d_in[6];
  const int* link_dst   = (const int*)d_in[7];
  const float* w_src_r1  = (const float*)d_in[8];
  const float* w_dst_r1  = (const float*)d_in[9];
  const float* a_r1      = (const float*)d_in[10];
  const float* b_r1      = (const float*)d_in[11];
  const float* w_src_rb1 = (const float*)d_in[12];
  const float* w_dst_rb1 = (const float*)d_in[13];
  const float* a_rb1     = (const float*)d_in[14];
  const float* b_rb1     = (const float*)d_in[15];
  const float* w_src_rb2 = (const float*)d_in[16];
  const float* w_dst_rb2 = (const float*)d_in[17];
  const float* a_rb2     = (const float*)d_in[18];
  const float* b_rb2     = (const float*)d_in[19];
  const float* w_src_l2  = (const float*)d_in[20];
  const float* w_dst_l2  = (const float*)d_in[21];
  const float* a_l2      = (const float*)d_in[22];
  const float* b_l2      = (const float*)d_in[23];
  const float* w_out     = (const float*)d_in[24];
  const float* b_out     = (const float*)d_in[25];
  float* out = (float*)d_out;

  char* ws = (char*)d_ws;
  size_t off = 0;
  auto alloc = [&](size_t bytes) -> void* {
    void* p = ws + off;
    off += (bytes + 255) & ~(size_t)255;
    return p;
  };

  __half* uh0 = (__half*)alloc((size_t)N_USER * 64 * 2);
  __half* u1  = (__half*)alloc((size_t)N_USER * 64 * 2);
  __half* u2  = (__half*)alloc((size_t)N_USER * 64 * 2);
  __half* u3  = (__half*)alloc((size_t)N_USER * 64 * 2);
  __half* i0  = (__half*)alloc((size_t)N_ITEM * 64 * 2);
  __half* ih1 = (__half*)alloc((size_t)N_ITEM * 64 * 2);

  int* mat     = (int*)alloc((size_t)MATN * 4);
  int* mscan   = (int*)alloc((size_t)MATN * 4);
  int* partials= (int*)alloc(256 * 4);
  int* grp     = (int*)alloc((size_t)(NTOT_NODES + 1) * 4);
  unsigned int* pairs = (unsigned int*)alloc((size_t)E_TOT * 4);
  int* col_all = (int*)alloc((size_t)E_TOT * 4);

  // ---- bucketed CSR build ----
  bucket_hist<<<3 * GPB, 256, 0, stream>>>(rate_dst, rb_dst, link_dst, mat);
  partial_kernel<<<NBP, 256, 0, stream>>>(mat, MATN, partials);
  scan_apply_fused<<<NBP, 256, 0, stream>>>(mat, MATN, partials, NBP, mscan);
  bucket_scatter<<<3 * GPB, 256, 0, stream>>>(rate_src, rate_dst, rb_src, rb_dst,
                                              link_src, link_dst, mscan, pairs);
  bucket_finalize<<<NBTOT, 256, 0, stream>>>(pairs, mscan, grp, col_all);

  int* rp_rate = grp;
  int* rp_rb   = grp + N_ITEM;
  int* rp_link = grp + N_ITEM + N_USER;

  // ---- node GEMMs ----
  gemm_user4<<<(N_USER + 63) / 64, 256, 0, stream>>>(
      h_user, w_src_r1, w_dst_rb1, w_dst_rb2, w_dst_l2, uh0, u1, u2, u3, N_USER);
  gemm_item2<<<(N_ITEM + 63) / 64, 256, 0, stream>>>(
      h_item, w_dst_r1, w_src_rb1, i0, ih1, N_ITEM);

  // ---- layer1: rate (user->item) || rated-by (item->user), fused, 8 nodes/wave ----
  {
    int nodes = N_ITEM + N_USER;
    gat8n_kernel<<<(nodes + 31) / 32, 256, 0, stream>>>(
        uh0, i0, rp_rate, a_r1,  b_r1,  i0, N_ITEM,
        ih1, u1, rp_rb,   a_rb1, b_rb1, u1, N_USER,
        col_all);
  }

  // ---- layer2 src transforms (fused pair, f16 in/out) ----
  {
    int nbA = (N_ITEM + 63) / 64;
    int nbB = (N_USER + 63) / 64;
    gemm_mid2x<<<nbA + nbB, 256, 0, stream>>>(
        i0, w_src_rb2, ih1, N_ITEM, nbA,
        u1, w_src_l2,  uh0, N_USER);
  }

  // ---- layer2: rated-by (item->user) || link (user->user), fused ----
  {
    int nodes = N_USER + N_USER;
    gat8n_kernel<<<(nodes + 31) / 32, 256, 0, stream>>>(
        ih1, u2, rp_rb,   a_rb2, b_rb2, u2, N_USER,
        uh0, u3, rp_link, a_l2,  b_l2,  u3, N_USER,
        col_all);
  }

  // ---- output projection ----
  final_kernel<<<(N_USER + 63) / 64, 256, 0, stream>>>(u2, u3, w_out, b_out, out, N_USER);
}

// Round 23
// 257.445 us; speedup vs baseline: 1.0189x; 1.0189x over previous
//
#include <hip/hip_runtime.h>
#include <hip/hip_fp16.h>
#include <math.h>

#define N_USER 50000
#define N_ITEM 100000
#define E_UI   1000000
#define E_UU   800000
#define E_TOT  (E_UI + E_UI + E_UU)
#define NTOT_NODES (N_ITEM + 2 * N_USER)
#define NEG_SLOPE 0.2f
#define LOG2E 1.4426950408889634f

#define NB0 391
#define NB1 196
#define NB2 196
#define NBTOT (NB0 + NB1 + NB2)   // 783
#define GPB 256
#define MATN (NBTOT * 256)        // 200448
#define NBP  ((MATN + 1023) / 1024)  // 196 partials

#define XS_STRIDE 68

typedef _Float16 h2v __attribute__((ext_vector_type(2)));

#if defined(__has_builtin)
#if __has_builtin(__builtin_amdgcn_fdot2)
#define HAS_FDOT2 1
#endif
#if __has_builtin(__builtin_elementwise_max)
#define HAS_EW_MAX 1
#endif
#if __has_builtin(__builtin_amdgcn_exp2f)
#define HAS_EXP2 1
#endif
#endif

__device__ __forceinline__ float fexp2(float x) {
#ifdef HAS_EXP2
  return __builtin_amdgcn_exp2f(x);
#else
  return exp2f(x);
#endif
}

__device__ __forceinline__ float fdot2acc(__half2 a, __half2 b, float c) {
#ifdef HAS_FDOT2
  return __builtin_amdgcn_fdot2(__builtin_bit_cast(h2v, a), __builtin_bit_cast(h2v, b), c, false);
#else
  float2 af = __half22float2(a), bf = __half22float2(b);
  return fmaf(af.x, bf.x, fmaf(af.y, bf.y, c));
#endif
}

__device__ __forceinline__ __half2 h2max(__half2 a, __half2 b) {
  h2v av = __builtin_bit_cast(h2v, a), bv = __builtin_bit_cast(h2v, b);
#ifdef HAS_EW_MAX
  h2v r = __builtin_elementwise_max(av, bv);
#else
  h2v r; r.x = av.x > bv.x ? av.x : bv.x; r.y = av.y > bv.y ? av.y : bv.y;
#endif
  return __builtin_bit_cast(__half2, r);
}

__device__ __forceinline__ __half2 h2min(__half2 a, __half2 b) {
  h2v av = __builtin_bit_cast(h2v, a), bv = __builtin_bit_cast(h2v, b);
#ifdef HAS_EW_MAX
  h2v r = __builtin_elementwise_min(av, bv);
#else
  h2v r; r.x = av.x < bv.x ? av.x : bv.x; r.y = av.y < bv.y ? av.y : bv.y;
#endif
  return __builtin_bit_cast(__half2, r);
}

// ---------------- bucket histogram ----------------

__global__ __launch_bounds__(256) void bucket_hist(const int* __restrict__ d0, const int* __restrict__ d1,
                                                   const int* __restrict__ d2, int* __restrict__ mat) {
  int gid = blockIdx.x >> 8;
  int g   = blockIdx.x & 255;
  const int* dst = gid == 0 ? d0 : (gid == 1 ? d1 : d2);
  int E    = (gid == 2) ? E_UU : E_UI;
  int NB   = (gid == 0) ? NB0 : NB1;
  int boff = (gid == 0) ? 0 : (gid == 1 ? NB0 : NB0 + NB1);
  __shared__ int cnt[NB0];
  for (int b = threadIdx.x; b < NB; b += 256) cnt[b] = 0;
  __syncthreads();
  int chunk = (E + 255) >> 8;
  int lo = g * chunk, hi = min(lo + chunk, E);
  for (int i = lo + threadIdx.x; i < hi; i += 256)
    atomicAdd(&cnt[dst[i] >> 8], 1);
  __syncthreads();
  for (int b = threadIdx.x; b < NB; b += 256)
    mat[(boff + b) * 256 + g] = cnt[b];
}

// ---------------- scan: partials + fused apply ----------------

__global__ __launch_bounds__(256) void partial_kernel(const int* __restrict__ counts, int n,
                                                      int* __restrict__ partials) {
  int t = threadIdx.x;
  int base = blockIdx.x * 1024 + t * 4;
  int s = 0;
  if (base + 3 < n) {
    int4 v = *(const int4*)(counts + base);
    s = v.x + v.y + v.z + v.w;
  } else {
    for (int i = base; i < n && i < base + 4; ++i) s += counts[i];
  }
  #pragma unroll
  for (int off = 1; off < 64; off <<= 1) s += __shfl_xor(s, off);
  __shared__ int ws[4];
  if ((t & 63) == 0) ws[t >> 6] = s;
  __syncthreads();
  if (t == 0) partials[blockIdx.x] = ws[0] + ws[1] + ws[2] + ws[3];
}

__global__ __launch_bounds__(256) void scan_apply_fused(const int* __restrict__ counts, int n,
                                                        const int* __restrict__ partials, int nbp,
                                                        int* __restrict__ outp) {
  __shared__ int sp[256];
  int t = threadIdx.x;
  sp[t] = (t < nbp) ? partials[t] : 0;
  __syncthreads();
  for (int off = 1; off < 256; off <<= 1) {
    int v = (t >= off) ? sp[t - off] : 0;
    __syncthreads();
    sp[t] += v;
    __syncthreads();
  }
  int block_off = (blockIdx.x == 0) ? 0 : sp[blockIdx.x - 1];

  int base = blockIdx.x * 1024 + t * 4;
  int4 v = make_int4(0, 0, 0, 0);
  if (base + 3 < n) {
    v = *(const int4*)(counts + base);
  } else {
    int* pv = &v.x;
    for (int i = 0; i < 4; ++i) if (base + i < n) pv[i] = counts[base + i];
  }
  int s = v.x + v.y + v.z + v.w;
  int lane = t & 63;
  int wv = t >> 6;
  int inc = s;
  #pragma unroll
  for (int off = 1; off < 64; off <<= 1) {
    int u = __shfl_up(inc, off);
    if (lane >= off) inc += u;
  }
  __shared__ int wsum[4];
  if (lane == 63) wsum[wv] = inc;
  __syncthreads();
  int woff = 0;
  for (int i = 0; i < wv; ++i) woff += wsum[i];
  int excl = woff + (inc - s) + block_off;
  int4 rp;
  rp.x = excl;
  rp.y = rp.x + v.x;
  rp.z = rp.y + v.y;
  rp.w = rp.z + v.z;
  if (base + 3 < n) {
    *(int4*)(outp + base) = rp;
  } else {
    int* pr = &rp.x;
    for (int i = 0; i < 4; ++i) if (base + i < n) outp[base + i] = pr[i];
  }
}

// ---------------- bucket scatter ----------------

__global__ __launch_bounds__(256) void bucket_scatter(const int* __restrict__ s0v, const int* __restrict__ d0,
                                                      const int* __restrict__ s1v, const int* __restrict__ d1,
                                                      const int* __restrict__ s2v, const int* __restrict__ d2,
                                                      const int* __restrict__ mscan, unsigned int* __restrict__ pairs) {
  int gid = blockIdx.x >> 8;
  int g   = blockIdx.x & 255;
  const int* src = gid == 0 ? s0v : (gid == 1 ? s1v : s2v);
  const int* dst = gid == 0 ? d0  : (gid == 1 ? d1  : d2);
  int E    = (gid == 2) ? E_UU : E_UI;
  int NB   = (gid == 0) ? NB0 : NB1;
  int boff = (gid == 0) ? 0 : (gid == 1 ? NB0 : NB0 + NB1);
  __shared__ int cur[NB0];
  for (int b = threadIdx.x; b < NB; b += 256) cur[b] = mscan[(boff + b) * 256 + g];
  __syncthreads();
  int chunk = (E + 255) >> 8;
  int lo = g * chunk, hi = min(lo + chunk, E);
  for (int i = lo + threadIdx.x; i < hi; i += 256) {
    int d = dst[i], s = src[i];
    int pos = atomicAdd(&cur[d >> 8], 1);
    pairs[pos] = ((unsigned)(d & 255) << 24) | (unsigned)s;
  }
}

// ---------------- bucket finalize ----------------

__global__ __launch_bounds__(256) void bucket_finalize(const unsigned int* __restrict__ pairs,
                                                       const int* __restrict__ mscan,
                                                       int* __restrict__ rp, int* __restrict__ col) {
  int gb = blockIdx.x;
  int t  = threadIdx.x;
  int gid  = (gb < NB0) ? 0 : (gb < NB0 + NB1 ? 1 : 2);
  int boff = (gid == 0) ? 0 : (gid == 1 ? NB0 : NB0 + NB1);
  int node_goff = (gid == 0) ? 0 : (gid == 1 ? N_ITEM : N_ITEM + N_USER);
  int n    = (gid == 0) ? N_ITEM : N_USER;
  int b_local = gb - boff;
  int bs = mscan[gb * 256];
  int be = (gb + 1 < NBTOT) ? mscan[(gb + 1) * 256] : E_TOT;

  __shared__ int cnt[256];
  __shared__ int curb[256];
  __shared__ int wsum[4];
  cnt[t] = 0;
  __syncthreads();
  for (int i = bs + t; i < be; i += 256)
    atomicAdd(&cnt[pairs[i] >> 24], 1);
  __syncthreads();

  int v = cnt[t];
  int lane = t & 63, wv = t >> 6;
  int inc = v;
  #pragma unroll
  for (int off = 1; off < 64; off <<= 1) {
    int u = __shfl_up(inc, off);
    if (lane >= off) inc += u;
  }
  if (lane == 63) wsum[wv] = inc;
  __syncthreads();
  int woff = 0;
  for (int i = 0; i < wv; ++i) woff += wsum[i];
  int base = bs + woff + (inc - v);

  int node_local = b_local * 256 + t;
  if (node_local < n) rp[node_goff + node_local] = base;
  if (gb == NBTOT - 1 && t == 255) rp[N_ITEM + 2 * N_USER] = E_TOT;
  curb[t] = base;
  __syncthreads();

  for (int i = bs + t; i < be; i += 256) {
    unsigned u = pairs[i];
    int p = atomicAdd(&curb[u >> 24], 1);
    col[p] = (int)(u & 0xFFFFFFu);
  }
}

// ---------------- GEMM building blocks (LDS-staged X, unroll-capped) ----------------

__device__ __forceinline__ void load_xtile(const float* __restrict__ X, float* Xs, int base, int N) {
  #pragma unroll
  for (int i = 0; i < 4; ++i) {
    int idx = threadIdx.x * 4 + i * 1024;
    int row = idx >> 6, colc = idx & 63;
    int grow = base + row;
    const float* src = X + (size_t)(grow < N ? grow : N - 1) * 64 + colc;
    *(float4*)(Xs + row * XS_STRIDE + colc) = *(const float4*)src;
  }
}

__device__ __forceinline__ void gemm_phase(const float* __restrict__ Wsrc, float* Ws,
                                           const float* x0, const float* x1,
                                           const float* x2, const float* x3, int c4,
                                           float4& acc0, float4& acc1, float4& acc2, float4& acc3) {
  __syncthreads();
  #pragma unroll
  for (int i = 0; i < 4; ++i) {
    int idx = threadIdx.x * 4 + i * 1024;
    *(float4*)(Ws + idx) = *(const float4*)(Wsrc + idx);
  }
  __syncthreads();
  acc0 = make_float4(0.f, 0.f, 0.f, 0.f);
  acc1 = acc0; acc2 = acc0; acc3 = acc0;
  #pragma unroll 4
  for (int k4 = 0; k4 < 64; k4 += 4) {
    float4 xa = *(const float4*)(x0 + k4);
    float4 xb = *(const float4*)(x1 + k4);
    float4 xc = *(const float4*)(x2 + k4);
    float4 xd = *(const float4*)(x3 + k4);
    #pragma unroll
    for (int kk = 0; kk < 4; ++kk) {
      float4 w = *(const float4*)(Ws + (k4 + kk) * 64 + c4);
      float sa = (&xa.x)[kk], sb = (&xb.x)[kk], sc = (&xc.x)[kk], sd = (&xd.x)[kk];
      acc0.x = fmaf(sa, w.x, acc0.x); acc0.y = fmaf(sa, w.y, acc0.y);
      acc0.z = fmaf(sa, w.z, acc0.z); acc0.w = fmaf(sa, w.w, acc0.w);
      acc1.x = fmaf(sb, w.x, acc1.x); acc1.y = fmaf(sb, w.y, acc1.y);
      acc1.z = fmaf(sb, w.z, acc1.z); acc1.w = fmaf(sb, w.w, acc1.w);
      acc2.x = fmaf(sc, w.x, acc2.x); acc2.y = fmaf(sc, w.y, acc2.y);
      acc2.z = fmaf(sc, w.z, acc2.z); acc2.w = fmaf(sc, w.w, acc2.w);
      acc3.x = fmaf(sd, w.x, acc3.x); acc3.y = fmaf(sd, w.y, acc3.y);
      acc3.z = fmaf(sd, w.z, acc3.z); acc3.w = fmaf(sd, w.w, acc3.w);
    }
  }
}

__device__ __forceinline__ void gemm_phase_h(const float* __restrict__ Wsrc, float* Ws,
                                             const __half* x0, const __half* x1,
                                             const __half* x2, const __half* x3, int c4,
                                             float4& acc0, float4& acc1, float4& acc2, float4& acc3) {
  __syncthreads();
  #pragma unroll
  for (int i = 0; i < 4; ++i) {
    int idx = threadIdx.x * 4 + i * 1024;
    *(float4*)(Ws + idx) = *(const float4*)(Wsrc + idx);
  }
  __syncthreads();
  acc0 = make_float4(0.f, 0.f, 0.f, 0.f);
  acc1 = acc0; acc2 = acc0; acc3 = acc0;
  #pragma unroll 4
  for (int k4 = 0; k4 < 64; k4 += 4) {
    uint2 ua = *(const uint2*)(x0 + k4);
    uint2 ub = *(const uint2*)(x1 + k4);
    uint2 uc = *(const uint2*)(x2 + k4);
    uint2 ud = *(const uint2*)(x3 + k4);
    float2 fa0 = __half22float2(__builtin_bit_cast(__half2, ua.x));
    float2 fa1 = __half22float2(__builtin_bit_cast(__half2, ua.y));
    float2 fb0 = __half22float2(__builtin_bit_cast(__half2, ub.x));
    float2 fb1 = __half22float2(__builtin_bit_cast(__half2, ub.y));
    float2 fc0 = __half22float2(__builtin_bit_cast(__half2, uc.x));
    float2 fc1 = __half22float2(__builtin_bit_cast(__half2, uc.y));
    float2 fd0 = __half22float2(__builtin_bit_cast(__half2, ud.x));
    float2 fd1 = __half22float2(__builtin_bit_cast(__half2, ud.y));
    float xav[4] = {fa0.x, fa0.y, fa1.x, fa1.y};
    float xbv[4] = {fb0.x, fb0.y, fb1.x, fb1.y};
    float xcv[4] = {fc0.x, fc0.y, fc1.x, fc1.y};
    float xdv[4] = {fd0.x, fd0.y, fd1.x, fd1.y};
    #pragma unroll
    for (int kk = 0; kk < 4; ++kk) {
      float4 w = *(const float4*)(Ws + (k4 + kk) * 64 + c4);
      float sa = xav[kk], sb = xbv[kk], sc = xcv[kk], sd = xdv[kk];
      acc0.x = fmaf(sa, w.x, acc0.x); acc0.y = fmaf(sa, w.y, acc0.y);
      acc0.z = fmaf(sa, w.z, acc0.z); acc0.w = fmaf(sa, w.w, acc0.w);
      acc1.x = fmaf(sb, w.x, acc1.x); acc1.y = fmaf(sb, w.y, acc1.y);
      acc1.z = fmaf(sb, w.z, acc1.z); acc1.w = fmaf(sb, w.w, acc1.w);
      acc2.x = fmaf(sc, w.x, acc2.x); acc2.y = fmaf(sc, w.y, acc2.y);
      acc2.z = fmaf(sc, w.z, acc2.z); acc2.w = fmaf(sc, w.w, acc2.w);
      acc3.x = fmaf(sd, w.x, acc3.x); acc3.y = fmaf(sd, w.y, acc3.y);
      acc3.z = fmaf(sd, w.z, acc3.z); acc3.w = fmaf(sd, w.w, acc3.w);
    }
  }
}

__device__ __forceinline__ void store4_f16(__half* __restrict__ Y, int r0, int r1, int r2, int r3,
                                           int N, int c4,
                                           const float4& a0, const float4& a1,
                                           const float4& a2, const float4& a3) {
  uint2 st;
  if (r0 < N) {
    st.x = __builtin_bit_cast(unsigned int, __floats2half2_rn(a0.x, a0.y));
    st.y = __builtin_bit_cast(unsigned int, __floats2half2_rn(a0.z, a0.w));
    *(uint2*)(Y + (size_t)r0 * 64 + c4) = st;
  }
  if (r1 < N) {
    st.x = __builtin_bit_cast(unsigned int, __floats2half2_rn(a1.x, a1.y));
    st.y = __builtin_bit_cast(unsigned int, __floats2half2_rn(a1.z, a1.w));
    *(uint2*)(Y + (size_t)r1 * 64 + c4) = st;
  }
  if (r2 < N) {
    st.x = __builtin_bit_cast(unsigned int, __floats2half2_rn(a2.x, a2.y));
    st.y = __builtin_bit_cast(unsigned int, __floats2half2_rn(a2.z, a2.w));
    *(uint2*)(Y + (size_t)r2 * 64 + c4) = st;
  }
  if (r3 < N) {
    st.x = __builtin_bit_cast(unsigned int, __floats2half2_rn(a3.x, a3.y));
    st.y = __builtin_bit_cast(unsigned int, __floats2half2_rn(a3.z, a3.w));
    *(uint2*)(Y + (size_t)r3 * 64 + c4) = st;
  }
}

__global__ __launch_bounds__(256) void gemm_user4(const float* __restrict__ X,
                                                  const float* __restrict__ W0, const float* __restrict__ W1,
                                                  const float* __restrict__ W2, const float* __restrict__ W3,
                                                  __half* __restrict__ Y0, __half* __restrict__ Y1,
                                                  __half* __restrict__ Y2, __half* __restrict__ Y3, int N) {
  __shared__ float Xs[64 * XS_STRIDE];
  __shared__ float Ws[64 * 64];
  int base = blockIdx.x * 64;
  load_xtile(X, Xs, base, N);
  int c4 = (threadIdx.x & 15) * 4;
  int rl = threadIdx.x >> 4;
  int r0 = base + rl, r1 = r0 + 16, r2 = r0 + 32, r3 = r0 + 48;
  const float* x0 = Xs + (rl +  0) * XS_STRIDE;
  const float* x1 = Xs + (rl + 16) * XS_STRIDE;
  const float* x2 = Xs + (rl + 32) * XS_STRIDE;
  const float* x3 = Xs + (rl + 48) * XS_STRIDE;
  float4 a0, a1, a2, a3;
  gemm_phase(W0, Ws, x0, x1, x2, x3, c4, a0, a1, a2, a3);
  store4_f16(Y0, r0, r1, r2, r3, N, c4, a0, a1, a2, a3);
  gemm_phase(W1, Ws, x0, x1, x2, x3, c4, a0, a1, a2, a3);
  store4_f16(Y1, r0, r1, r2, r3, N, c4, a0, a1, a2, a3);
  gemm_phase(W2, Ws, x0, x1, x2, x3, c4, a0, a1, a2, a3);
  store4_f16(Y2, r0, r1, r2, r3, N, c4, a0, a1, a2, a3);
  gemm_phase(W3, Ws, x0, x1, x2, x3, c4, a0, a1, a2, a3);
  store4_f16(Y3, r0, r1, r2, r3, N, c4, a0, a1, a2, a3);
}

__global__ __launch_bounds__(256) void gemm_item2(const float* __restrict__ X,
                                                  const float* __restrict__ W0, const float* __restrict__ W1,
                                                  __half* __restrict__ Y0, __half* __restrict__ Y1, int N) {
  __shared__ float Xs[64 * XS_STRIDE];
  __shared__ float Ws[64 * 64];
  int base = blockIdx.x * 64;
  load_xtile(X, Xs, base, N);
  int c4 = (threadIdx.x & 15) * 4;
  int rl = threadIdx.x >> 4;
  int r0 = base + rl, r1 = r0 + 16, r2 = r0 + 32, r3 = r0 + 48;
  const float* x0 = Xs + (rl +  0) * XS_STRIDE;
  const float* x1 = Xs + (rl + 16) * XS_STRIDE;
  const float* x2 = Xs + (rl + 32) * XS_STRIDE;
  const float* x3 = Xs + (rl + 48) * XS_STRIDE;
  float4 a0, a1, a2, a3;
  gemm_phase(W0, Ws, x0, x1, x2, x3, c4, a0, a1, a2, a3);
  store4_f16(Y0, r0, r1, r2, r3, N, c4, a0, a1, a2, a3);
  gemm_phase(W1, Ws, x0, x1, x2, x3, c4, a0, a1, a2, a3);
  store4_f16(Y1, r0, r1, r2, r3, N, c4, a0, a1, a2, a3);
}

__global__ __launch_bounds__(256) void gemm_mid2x(const __half* __restrict__ XA, const float* __restrict__ WA,
                                                  __half* __restrict__ YA, int NA, int nbA,
                                                  const __half* __restrict__ XB, const float* __restrict__ WB,
                                                  __half* __restrict__ YB, int NB_) {
  __shared__ float Ws[64 * 64];
  const __half* X; const float* W; __half* Y; int N; int base;
  if ((int)blockIdx.x < nbA) {
    X = XA; W = WA; Y = YA; N = NA; base = blockIdx.x * 64;
  } else {
    X = XB; W = WB; Y = YB; N = NB_; base = (blockIdx.x - nbA) * 64;
  }
  int c4 = (threadIdx.x & 15) * 4;
  int rl = threadIdx.x >> 4;
  int r0 = base + rl, r1 = r0 + 16, r2 = r0 + 32, r3 = r0 + 48;
  const __half* x0 = X + (size_t)(r0 < N ? r0 : N - 1) * 64;
  const __half* x1 = X + (size_t)(r1 < N ? r1 : N - 1) * 64;
  const __half* x2 = X + (size_t)(r2 < N ? r2 : N - 1) * 64;
  const __half* x3 = X + (size_t)(r3 < N ? r3 : N - 1) * 64;
  float4 a0, a1, a2, a3;
  gemm_phase_h(W, Ws, x0, x1, x2, x3, c4, a0, a1, a2, a3);
  store4_f16(Y, r0, r1, r2, r3, N, c4, a0, a1, a2, a3);
}

// ---------------- fused GATv2 v6h: 8 nodes/wave, f16 hd + f16 out ----------------

__global__ __launch_bounds__(256) void gat8n_kernel(
    const __half* __restrict__ hsA, const __half* __restrict__ hdAp,
    const int* __restrict__ rpA, const float* __restrict__ attnA, const float* __restrict__ biasA,
    __half* __restrict__ outA, int NdA,
    const __half* __restrict__ hsB, const __half* __restrict__ hdBp,
    const int* __restrict__ rpB, const float* __restrict__ attnB, const float* __restrict__ biasB,
    __half* __restrict__ outB, int NdB,
    const int* __restrict__ col) {
  int w = (blockIdx.x * blockDim.x + threadIdx.x) >> 6;
  int grp = (threadIdx.x >> 3) & 7;    // 8 groups per wave
  int q   = threadIdx.x & 7;           // lane-in-group: dims [q*8, q*8+8)
  int node = w * 8 + grp;
  bool valid = node < NdA + NdB;
  bool inA = node < NdA;
  const __half* hs  = inA ? hsA  : hsB;
  const __half* hd  = inA ? hdAp : hdBp;
  const int* rp     = inA ? rpA  : rpB;
  const float* attn = inA ? attnA : attnB;
  const float* bias = inA ? biasA : biasB;
  __half* outp      = inA ? outA : outB;
  int nn = inA ? node : node - NdA;
  if (!valid) nn = 0;
  int s0 = valid ? rp[nn] : 0;
  int s1 = valid ? rp[nn + 1] : 0;

  const __half2 C02 = __floats2half2_rn(NEG_SLOPE, NEG_SLOPE);
  const __half2 Z   = __floats2half2_rn(0.f, 0.f);

  __half2 hd2[4], a2[4];
  {
    uint4 hv = *(const uint4*)(hd + (size_t)nn * 64 + q * 8);   // 8 f16 dims
    hd2[0] = __builtin_bit_cast(__half2, hv.x);
    hd2[1] = __builtin_bit_cast(__half2, hv.y);
    hd2[2] = __builtin_bit_cast(__half2, hv.z);
    hd2[3] = __builtin_bit_cast(__half2, hv.w);
    const float* ap = attn + q * 8;
    #pragma unroll
    for (int i = 0; i < 2; ++i) {
      float4 v = *(const float4*)(ap + i * 4);
      a2[2 * i]     = __floats2half2_rn(v.x * LOG2E, v.y * LOG2E);
      a2[2 * i + 1] = __floats2half2_rn(v.z * LOG2E, v.w * LOG2E);
    }
  }

  float m = -1e30f, den = 0.f;
  float num[8];
  #pragma unroll
  for (int i = 0; i < 8; ++i) num[i] = 0.f;

  for (int e = s0; e < s1; e += 4) {
    bool h1 = (e + 1) < s1, h2c = (e + 2) < s1, h3 = (e + 3) < s1;
    int sa = col[e];
    int sb = col[h1 ? e + 1 : e];
    int sc = col[h2c ? e + 2 : e];
    int sd = col[h3 ? e + 3 : e];
    uint4 ra = *(const uint4*)(hs + (size_t)sa * 64 + q * 8);
    uint4 rb = *(const uint4*)(hs + (size_t)sb * 64 + q * 8);
    uint4 rc = *(const uint4*)(hs + (size_t)sc * 64 + q * 8);
    uint4 rd = *(const uint4*)(hs + (size_t)sd * 64 + q * 8);
    unsigned rau[4] = {ra.x, ra.y, ra.z, ra.w};
    unsigned rbu[4] = {rb.x, rb.y, rb.z, rb.w};
    unsigned rcu[4] = {rc.x, rc.y, rc.z, rc.w};
    unsigned rdu[4] = {rd.x, rd.y, rd.z, rd.w};

    float ta = 0.f, tb = 0.f, tc = 0.f, td = 0.f;
    #pragma unroll
    for (int i = 0; i < 4; ++i) {
      __half2 xa = __hadd2(__builtin_bit_cast(__half2, rau[i]), hd2[i]);
      ta = fdot2acc(a2[i], __hfma2(C02, h2min(xa, Z), h2max(xa, Z)), ta);
      __half2 xb = __hadd2(__builtin_bit_cast(__half2, rbu[i]), hd2[i]);
      tb = fdot2acc(a2[i], __hfma2(C02, h2min(xb, Z), h2max(xb, Z)), tb);
      __half2 xc = __hadd2(__builtin_bit_cast(__half2, rcu[i]), hd2[i]);
      tc = fdot2acc(a2[i], __hfma2(C02, h2min(xc, Z), h2max(xc, Z)), tc);
      __half2 xd = __hadd2(__builtin_bit_cast(__half2, rdu[i]), hd2[i]);
      td = fdot2acc(a2[i], __hfma2(C02, h2min(xd, Z), h2max(xd, Z)), td);
    }
    #pragma unroll
    for (int off = 1; off < 8; off <<= 1) {
      ta += __shfl_xor(ta, off);
      tb += __shfl_xor(tb, off);
      tc += __shfl_xor(tc, off);
      td += __shfl_xor(td, off);
    }
    if (!h1)  tb = -1e30f;
    if (!h2c) tc = -1e30f;
    if (!h3)  td = -1e30f;

    float tp = fmaxf(fmaxf(ta, tb), fmaxf(tc, td));
    float dd = tp - m;
    if (dd > 11.5f) {                 // defer-max (log2 units)
      float sc0 = fexp2(-dd);
      den *= sc0;
      #pragma unroll
      for (int i = 0; i < 8; ++i) num[i] *= sc0;
      m = tp;
    }
    float pa = fexp2(ta - m);
    float pb = fexp2(tb - m);
    float pc = fexp2(tc - m);
    float pd = fexp2(td - m);
    den += (pa + pb) + (pc + pd);
    __half2 pab = __floats2half2_rn(pa, pb);
    __half2 pcd = __floats2half2_rn(pc, pd);

    #pragma unroll
    for (int i = 0; i < 4; ++i) {
      unsigned lo_ab = (rau[i] & 0xFFFFu) | (rbu[i] << 16);
      unsigned hi_ab = (rau[i] >> 16) | (rbu[i] & 0xFFFF0000u);
      unsigned lo_cd = (rcu[i] & 0xFFFFu) | (rdu[i] << 16);
      unsigned hi_cd = (rcu[i] >> 16) | (rdu[i] & 0xFFFF0000u);
      num[2 * i]     = fdot2acc(__builtin_bit_cast(__half2, lo_cd), pcd,
                       fdot2acc(__builtin_bit_cast(__half2, lo_ab), pab, num[2 * i]));
      num[2 * i + 1] = fdot2acc(__builtin_bit_cast(__half2, hi_cd), pcd,
                       fdot2acc(__builtin_bit_cast(__half2, hi_ab), pab, num[2 * i + 1]));
    }
  }

  if (valid) {
    float inv = 1.f / fmaxf(den, 1e-9f);
    const float* bp = bias + q * 8;
    float4 b0 = *(const float4*)(bp);
    float4 b1 = *(const float4*)(bp + 4);
    uint4 st;
    st.x = __builtin_bit_cast(unsigned int,
        __floats2half2_rn(fmaf(num[0], inv, b0.x), fmaf(num[1], inv, b0.y)));
    st.y = __builtin_bit_cast(unsigned int,
        __floats2half2_rn(fmaf(num[2], inv, b0.z), fmaf(num[3], inv, b0.w)));
    st.z = __builtin_bit_cast(unsigned int,
        __floats2half2_rn(fmaf(num[4], inv, b1.x), fmaf(num[5], inv, b1.y)));
    st.w = __builtin_bit_cast(unsigned int,
        __floats2half2_rn(fmaf(num[6], inv, b1.z), fmaf(num[7], inv, b1.w)));
    *(uint4*)(outp + (size_t)nn * 64 + q * 8) = st;
  }
}

// ---------------- final: out = [A|B] @ Wout + bout (A,B f16) ----------------

__global__ __launch_bounds__(256) void final_kernel(const __half* __restrict__ A, const __half* __restrict__ B,
                                                    const float* __restrict__ W, const float* __restrict__ bias,
                                                    float* __restrict__ Y, int N) {
  __shared__ float Ws[128 * 64];
  #pragma unroll
  for (int i = 0; i < 8; ++i) {
    int idx = threadIdx.x * 4 + i * 1024;
    *(float4*)(Ws + idx) = *(const float4*)(W + idx);
  }
  __syncthreads();
  int c4 = (threadIdx.x & 15) * 4;
  int rl = threadIdx.x >> 4;
  int base = blockIdx.x * 64;

  float4 b4 = *(const float4*)(bias + c4);

  #pragma unroll
  for (int rr = 0; rr < 4; ++rr) {
    int row = base + rr * 16 + rl;
    if (row >= N) continue;
    const __half* ar = A + (size_t)row * 64;
    const __half* br = B + (size_t)row * 64;
    float4 acc = b4;
    #pragma unroll 4
    for (int k4 = 0; k4 < 64; k4 += 4) {
      uint2 ua = *(const uint2*)(ar + k4);
      uint2 ub = *(const uint2*)(br + k4);
      float2 fa0 = __half22float2(__builtin_bit_cast(__half2, ua.x));
      float2 fa1 = __half22float2(__builtin_bit_cast(__half2, ua.y));
      float2 fb0 = __half22float2(__builtin_bit_cast(__half2, ub.x));
      float2 fb1 = __half22float2(__builtin_bit_cast(__half2, ub.y));
      float xav[4] = {fa0.x, fa0.y, fa1.x, fa1.y};
      float xbv[4] = {fb0.x, fb0.y, fb1.x, fb1.y};
      #pragma unroll
      for (int kk = 0; kk < 4; ++kk) {
        float4 wa = *(const float4*)(Ws + (k4 + kk) * 64 + c4);
        float4 wb = *(const float4*)(Ws + (64 + k4 + kk) * 64 + c4);
        float xsa = xav[kk], xsb = xbv[kk];
        acc.x = fmaf(xsa, wa.x, acc.x); acc.x = fmaf(xsb, wb.x, acc.x);
        acc.y = fmaf(xsa, wa.y, acc.y); acc.y = fmaf(xsb, wb.y, acc.y);
        acc.z = fmaf(xsa, wa.z, acc.z); acc.z = fmaf(xsb, wb.z, acc.z);
        acc.w = fmaf(xsa, wa.w, acc.w); acc.w = fmaf(xsb, wb.w, acc.w);
      }
    }
    *(float4*)(Y + (size_t)row * 64 + c4) = acc;
  }
}

// ---------------- launch ----------------

extern "C" void kernel_launch(void* const* d_in, const int* in_sizes, int n_in,
                              void* d_out, int out_size, void* d_ws, size_t ws_size,
                              hipStream_t stream) {
  const float* h_user   = (const float*)d_in[0];
  const float* h_item   = (const float*)d_in[1];
  const int* rate_src   = (const int*)d_in[2];
  const int* rate_dst   = (const int*)d_in[3];
  const int* rb_src     = (const int*)d_in[4];
  const int* rb_dst     = (const int*)d_in[5];
  const int* link_src   = (const int*)d_in[6];
  const int* link_dst   = (const int*)d_in[7];
  const float* w_src_r1  = (const float*)d_in[8];
  const float* w_dst_r1  = (const float*)d_in[9];
  const float* a_r1      = (const float*)d_in[10];
  const float* b_r1      = (const float*)d_in[11];
  const float* w_src_rb1 = (const float*)d_in[12];
  const float* w_dst_rb1 = (const float*)d_in[13];
  const float* a_rb1     = (const float*)d_in[14];
  const float* b_rb1     = (const float*)d_in[15];
  const float* w_src_rb2 = (const float*)d_in[16];
  const float* w_dst_rb2 = (const float*)d_in[17];
  const float* a_rb2     = (const float*)d_in[18];
  const float* b_rb2     = (const float*)d_in[19];
  const float* w_src_l2  = (const float*)d_in[20];
  const float* w_dst_l2  = (const float*)d_in[21];
  const float* a_l2      = (const float*)d_in[22];
  const float* b_l2      = (const float*)d_in[23];
  const float* w_out     = (const float*)d_in[24];
  const float* b_out     = (const float*)d_in[25];
  float* out = (float*)d_out;

  char* ws = (char*)d_ws;
  size_t off = 0;
  auto alloc = [&](size_t bytes) -> void* {
    void* p = ws + off;
    off += (bytes + 255) & ~(size_t)255;
    return p;
  };

  __half* uh0 = (__half*)alloc((size_t)N_USER * 64 * 2);
  __half* u1  = (__half*)alloc((size_t)N_USER * 64 * 2);
  __half* u2  = (__half*)alloc((size_t)N_USER * 64 * 2);
  __half* u3  = (__half*)alloc((size_t)N_USER * 64 * 2);
  __half* i0  = (__half*)alloc((size_t)N_ITEM * 64 * 2);
  __half* ih1 = (__half*)alloc((size_t)N_ITEM * 64 * 2);

  int* mat     = (int*)alloc((size_t)MATN * 4);
  int* mscan   = (int*)alloc((size_t)MATN * 4);
  int* partials= (int*)alloc(256 * 4);
  int* grp     = (int*)alloc((size_t)(NTOT_NODES + 1) * 4);
  unsigned int* pairs = (unsigned int*)alloc((size_t)E_TOT * 4);
  int* col_all = (int*)alloc((size_t)E_TOT * 4);

  // ---- bucketed CSR build ----
  bucket_hist<<<3 * GPB, 256, 0, stream>>>(rate_dst, rb_dst, link_dst, mat);
  partial_kernel<<<NBP, 256, 0, stream>>>(mat, MATN, partials);
  scan_apply_fused<<<NBP, 256, 0, stream>>>(mat, MATN, partials, NBP, mscan);
  bucket_scatter<<<3 * GPB, 256, 0, stream>>>(rate_src, rate_dst, rb_src, rb_dst,
                                              link_src, link_dst, mscan, pairs);
  bucket_finalize<<<NBTOT, 256, 0, stream>>>(pairs, mscan, grp, col_all);

  int* rp_rate = grp;
  int* rp_rb   = grp + N_ITEM;
  int* rp_link = grp + N_ITEM + N_USER;

  // ---- node GEMMs ----
  gemm_user4<<<(N_USER + 63) / 64, 256, 0, stream>>>(
      h_user, w_src_r1, w_dst_rb1, w_dst_rb2, w_dst_l2, uh0, u1, u2, u3, N_USER);
  gemm_item2<<<(N_ITEM + 63) / 64, 256, 0, stream>>>(
      h_item, w_dst_r1, w_src_rb1, i0, ih1, N_ITEM);

  // ---- layer1: rate (user->item) || rated-by (item->user), fused, 8 nodes/wave ----
  {
    int nodes = N_ITEM + N_USER;
    gat8n_kernel<<<(nodes + 31) / 32, 256, 0, stream>>>(
        uh0, i0, rp_rate, a_r1,  b_r1,  i0, N_ITEM,
        ih1, u1, rp_rb,   a_rb1, b_rb1, u1, N_USER,
        col_all);
  }

  // ---- layer2 src transforms (fused pair, f16 in/out) ----
  {
    int nbA = (N_ITEM + 63) / 64;
    int nbB = (N_USER + 63) / 64;
    gemm_mid2x<<<nbA + nbB, 256, 0, stream>>>(
        i0, w_src_rb2, ih1, N_ITEM, nbA,
        u1, w_src_l2,  uh0, N_USER);
  }

  // ---- layer2: rated-by (item->user) || link (user->user), fused ----
  {
    int nodes = N_USER + N_USER;
    gat8n_kernel<<<(nodes + 31) / 32, 256, 0, stream>>>(
        ih1, u2, rp_rb,   a_rb2, b_rb2, u2, N_USER,
        uh0, u3, rp_link, a_l2,  b_l2,  u3, N_USER,
        col_all);
  }

  // ---- output projection ----
  final_kernel<<<(N_USER + 63) / 64, 256, 0, stream>>>(u2, u3, w_out, b_out, out, N_USER);
}